// Round 1
// baseline (70.305 us; speedup 1.0000x reference)
//
#include <hip/hip_runtime.h>

#define NB 16384       // bags
#define DIM 128
#define PRED_W 512     // 4 * DIM
#define NPART NB       // one partial per block

__global__ __launch_bounds__(256) void pool4_kernel(
    const int* __restrict__ idx0, const int* __restrict__ len0,
    const float* __restrict__ emb0, const float* __restrict__ pw0,
    const int* __restrict__ idx1, const int* __restrict__ len1,
    const float* __restrict__ emb1, const float* __restrict__ pw1,
    const int* __restrict__ idx2, const int* __restrict__ len2,
    const float* __restrict__ emb2, const float* __restrict__ pw2,
    const int* __restrict__ idx3, const int* __restrict__ len3,
    const float* __restrict__ emb3, const float* __restrict__ pw3,
    float* __restrict__ pred,      // d_out + 1 (4-byte aligned only)
    float* __restrict__ partials)  // d_ws, NPART floats
{
    const int b    = blockIdx.x;
    const int wave = threadIdx.x >> 6;   // 0..3 -> feature id
    const int lane = threadIdx.x & 63;

    const int*   idx; const int* len; const float* emb; const float* pw; int L;
    switch (wave) {
        case 0:  idx = idx0; len = len0; emb = emb0; pw = pw0; L = 10; break;
        case 1:  idx = idx1; len = len1; emb = emb1; pw = pw1; L = 10; break;
        case 2:  idx = idx2; len = len2; emb = emb2; pw = pw2; L = 12; break;
        default: idx = idx3; len = len3; emb = emb3; pw = pw3; L = 12; break;
    }

    const int n = len[b];
    const int* __restrict__ bag = idx + (size_t)b * L;

    float ax = 0.f, ay = 0.f;
    for (int l = 0; l < n; ++l) {
        const int   r = bag[l];          // broadcast load (all lanes same addr)
        const float w = pw[l];
        const float2 v = *reinterpret_cast<const float2*>(
            emb + (size_t)r * DIM + 2 * lane);   // 512B coalesced row read
        ax = fmaf(w, v.x, ax);
        ay = fmaf(w, v.y, ay);
    }

    // pred store: scalar (pred base is only 4B aligned)
    float* o = pred + (size_t)b * PRED_W + wave * DIM + 2 * lane;
    o[0] = ax;
    o[1] = ay;

    // loss partial: wave reduce -> block reduce -> one partial per block
    float s = ax + ay;
    #pragma unroll
    for (int off = 32; off; off >>= 1) s += __shfl_down(s, off, 64);

    __shared__ float ws[4];
    if (lane == 0) ws[wave] = s;
    __syncthreads();
    if (threadIdx.x == 0) partials[b] = ws[0] + ws[1] + ws[2] + ws[3];
}

__global__ __launch_bounds__(1024) void reduce_kernel(
    const float* __restrict__ partials, float* __restrict__ loss_out)
{
    float s = 0.f;
    for (int i = threadIdx.x; i < NPART; i += 1024) s += partials[i];

    #pragma unroll
    for (int off = 32; off; off >>= 1) s += __shfl_down(s, off, 64);

    __shared__ float ws[16];
    const int wave = threadIdx.x >> 6, lane = threadIdx.x & 63;
    if (lane == 0) ws[wave] = s;
    __syncthreads();
    if (threadIdx.x == 0) {
        float t = 0.f;
        #pragma unroll
        for (int i = 0; i < 16; ++i) t += ws[i];
        loss_out[0] = t / (float)((size_t)NB * PRED_W);
    }
}

extern "C" void kernel_launch(void* const* d_in, const int* in_sizes, int n_in,
                              void* d_out, int out_size, void* d_ws, size_t ws_size,
                              hipStream_t stream) {
    // setup_inputs() dict order: per feature f: idx{f}, len{f}, emb{f}, pw{f}
    const int*   idx0 = (const int*)  d_in[0];
    const int*   len0 = (const int*)  d_in[1];
    const float* emb0 = (const float*)d_in[2];
    const float* pw0  = (const float*)d_in[3];
    const int*   idx1 = (const int*)  d_in[4];
    const int*   len1 = (const int*)  d_in[5];
    const float* emb1 = (const float*)d_in[6];
    const float* pw1  = (const float*)d_in[7];
    const int*   idx2 = (const int*)  d_in[8];
    const int*   len2 = (const int*)  d_in[9];
    const float* emb2 = (const float*)d_in[10];
    const float* pw2  = (const float*)d_in[11];
    const int*   idx3 = (const int*)  d_in[12];
    const int*   len3 = (const int*)  d_in[13];
    const float* emb3 = (const float*)d_in[14];
    const float* pw3  = (const float*)d_in[15];

    float* out = (float*)d_out;          // out[0] = loss, out+1 = pred
    float* partials = (float*)d_ws;      // NPART floats

    pool4_kernel<<<NB, 256, 0, stream>>>(
        idx0, len0, emb0, pw0,
        idx1, len1, emb1, pw1,
        idx2, len2, emb2, pw2,
        idx3, len3, emb3, pw3,
        out + 1, partials);

    reduce_kernel<<<1, 1024, 0, stream>>>(partials, out);
}

// Round 2
// 39.236 us; speedup vs baseline: 1.7918x; 1.7918x over previous
//
#include <hip/hip_runtime.h>

#define NB 16384       // bags
#define DIM 128
#define PRED_W 512     // 4 * DIM
#define NPART NB       // one partial per block

template<int L>
__device__ __forceinline__ void pool_one(
    const int* __restrict__ idx, const int* __restrict__ len,
    const float* __restrict__ emb, const float* __restrict__ pw,
    int b, int lane, float& ax, float& ay)
{
    const int n = len[b];                       // wave-uniform
    const int* __restrict__ bag = idx + (size_t)b * L;

    // 1) all idx loads up front (broadcast addresses, coalesce to 1 req each)
    int r[L];
    #pragma unroll
    for (int l = 0; l < L; ++l) r[l] = bag[l];

    // 2) issue all row gathers back-to-back -> up to L outstanding 8B loads/lane
    float2 v[L];
    #pragma unroll
    for (int l = 0; l < L; ++l)
        if (l < n)                              // wave-uniform branch, no divergence
            v[l] = *reinterpret_cast<const float2*>(
                emb + (size_t)r[l] * DIM + 2 * lane);

    // 3) accumulate
    #pragma unroll
    for (int l = 0; l < L; ++l)
        if (l < n) {
            const float w = pw[l];
            ax = fmaf(w, v[l].x, ax);
            ay = fmaf(w, v[l].y, ay);
        }
}

__global__ __launch_bounds__(256) void pool4_kernel(
    const int* __restrict__ idx0, const int* __restrict__ len0,
    const float* __restrict__ emb0, const float* __restrict__ pw0,
    const int* __restrict__ idx1, const int* __restrict__ len1,
    const float* __restrict__ emb1, const float* __restrict__ pw1,
    const int* __restrict__ idx2, const int* __restrict__ len2,
    const float* __restrict__ emb2, const float* __restrict__ pw2,
    const int* __restrict__ idx3, const int* __restrict__ len3,
    const float* __restrict__ emb3, const float* __restrict__ pw3,
    float* __restrict__ pred,      // d_out + 1 (4-byte aligned only)
    float* __restrict__ partials)  // d_ws, NPART floats
{
    const int b    = blockIdx.x;
    const int wave = threadIdx.x >> 6;   // 0..3 -> feature id
    const int lane = threadIdx.x & 63;

    float ax = 0.f, ay = 0.f;
    switch (wave) {
        case 0:  pool_one<10>(idx0, len0, emb0, pw0, b, lane, ax, ay); break;
        case 1:  pool_one<10>(idx1, len1, emb1, pw1, b, lane, ax, ay); break;
        case 2:  pool_one<12>(idx2, len2, emb2, pw2, b, lane, ax, ay); break;
        default: pool_one<12>(idx3, len3, emb3, pw3, b, lane, ax, ay); break;
    }

    // pred store: scalar (pred base is only 4B aligned)
    float* o = pred + (size_t)b * PRED_W + wave * DIM + 2 * lane;
    o[0] = ax;
    o[1] = ay;

    // loss partial: wave reduce -> block reduce -> one partial per block
    float s = ax + ay;
    #pragma unroll
    for (int off = 32; off; off >>= 1) s += __shfl_down(s, off, 64);

    __shared__ float ws[4];
    if (lane == 0) ws[wave] = s;
    __syncthreads();
    if (threadIdx.x == 0) partials[b] = ws[0] + ws[1] + ws[2] + ws[3];
}

__global__ __launch_bounds__(1024) void reduce_kernel(
    const float* __restrict__ partials, float* __restrict__ loss_out)
{
    // 16384 floats = 4096 float4s, 1024 threads x 4
    float s = 0.f;
    const float4* p4 = reinterpret_cast<const float4*>(partials);
    #pragma unroll
    for (int i = 0; i < 4; ++i) {
        float4 v = p4[threadIdx.x + i * 1024];
        s += (v.x + v.y) + (v.z + v.w);
    }

    #pragma unroll
    for (int off = 32; off; off >>= 1) s += __shfl_down(s, off, 64);

    __shared__ float ws[16];
    const int wave = threadIdx.x >> 6, lane = threadIdx.x & 63;
    if (lane == 0) ws[wave] = s;
    __syncthreads();
    if (threadIdx.x == 0) {
        float t = 0.f;
        #pragma unroll
        for (int i = 0; i < 16; ++i) t += ws[i];
        loss_out[0] = t / (float)((size_t)NB * PRED_W);
    }
}

extern "C" void kernel_launch(void* const* d_in, const int* in_sizes, int n_in,
                              void* d_out, int out_size, void* d_ws, size_t ws_size,
                              hipStream_t stream) {
    // setup_inputs() dict order: per feature f: idx{f}, len{f}, emb{f}, pw{f}
    const int*   idx0 = (const int*)  d_in[0];
    const int*   len0 = (const int*)  d_in[1];
    const float* emb0 = (const float*)d_in[2];
    const float* pw0  = (const float*)d_in[3];
    const int*   idx1 = (const int*)  d_in[4];
    const int*   len1 = (const int*)  d_in[5];
    const float* emb1 = (const float*)d_in[6];
    const float* pw1  = (const float*)d_in[7];
    const int*   idx2 = (const int*)  d_in[8];
    const int*   len2 = (const int*)  d_in[9];
    const float* emb2 = (const float*)d_in[10];
    const float* pw2  = (const float*)d_in[11];
    const int*   idx3 = (const int*)  d_in[12];
    const int*   len3 = (const int*)  d_in[13];
    const float* emb3 = (const float*)d_in[14];
    const float* pw3  = (const float*)d_in[15];

    float* out = (float*)d_out;          // out[0] = loss, out+1 = pred
    float* partials = (float*)d_ws;      // NPART floats

    pool4_kernel<<<NB, 256, 0, stream>>>(
        idx0, len0, emb0, pw0,
        idx1, len1, emb1, pw1,
        idx2, len2, emb2, pw2,
        idx3, len3, emb3, pw3,
        out + 1, partials);

    reduce_kernel<<<1, 1024, 0, stream>>>(partials, out);
}